// Round 3
// 240.631 us; speedup vs baseline: 1.0131x; 1.0131x over previous
//
#include <hip/hip_runtime.h>

// MultiheadAttention N=4096, d_model=512, 8 heads, d_head=64.
// fp32 inputs/output, f16 MFMA pipeline (f16 has 3 more mantissa bits than
// bf16 and enables single-instruction v_cvt_pkrtz_f16_f32 packing in the
// attn softmax hot loop -- the kernel was VALU-bound on pack_bf16).
// pack_mask -> transposed 2MB bitmap mbT[word][row] ; convert fp32->f16 ;
// qkv GEMM BN=64 (Q scaled 0.125*log2e, V transposed per-head) ; split-KV
// flash attention (4-wave blocks, 128 q-rows/block for 4 blocks/CU
// occupancy, double-buffered staging, hoisted LDS addressing + unroll-2 so
// buffer base is an offset immediate, running global pointers, zero-shuffle
// PV) ; reduce partials ; output GEMM BN=64.

typedef __attribute__((ext_vector_type(8))) _Float16 f16x8;
typedef __attribute__((ext_vector_type(2))) __fp16 fp16x2_raw;  // cvt_pkrtz ret
typedef __attribute__((ext_vector_type(4))) float f32x4;

#define N_TOK 4096
#define QSCALE 0.18033688f  // 0.125 * log2(e)

__device__ __forceinline__ unsigned short f2h(float f) {
  union { _Float16 h; unsigned short u; } c;
  c.h = (_Float16)f;
  return c.u;
}
// packed f32x2 -> f16x2 in ONE instruction (v_cvt_pkrtz_f16_f32).
__device__ __forceinline__ unsigned pack_f16(float a, float b) {
  union { fp16x2_raw h; unsigned u; } c;
  c.h = __builtin_amdgcn_cvt_pkrtz(a, b);
  return c.u;
}
__device__ __forceinline__ f32x4 mfma16(f16x8 a, f16x8 b, f32x4 c) {
  return __builtin_amdgcn_mfma_f32_16x16x32_f16(a, b, c, 0, 0, 0);
}
__device__ __forceinline__ float fast_exp2(float x) {
#if __has_builtin(__builtin_amdgcn_exp2f)
  return __builtin_amdgcn_exp2f(x);
#else
  return exp2f(x);
#endif
}

// ---------------- mask bit-pack -> TRANSPOSED u64 bitsT[64 words][4096 rows] -
// mask proven int32 {0,1} by rounds 2-7 (u8 misread would fail absmax).
__global__ __launch_bounds__(256) void pack_mask_kernel(
    const int* __restrict__ m, unsigned long long* __restrict__ bitsT) {
  int gt = blockIdx.x * 256 + threadIdx.x;
  int wave = gt >> 6;       // 0..65535
  int lane = threadIdx.x & 63;
  int row = wave >> 4;      // mask row
  int sub = wave & 15;      // 256-elem j-slice within the row
  int base = wave * 256;
  unsigned long long b0 = __ballot(m[base + 0 * 64 + lane] != 0);
  unsigned long long b1 = __ballot(m[base + 1 * 64 + lane] != 0);
  unsigned long long b2 = __ballot(m[base + 2 * 64 + lane] != 0);
  unsigned long long b3 = __ballot(m[base + 3 * 64 + lane] != 0);
  if (lane < 4) {
    unsigned long long bl = lane == 0 ? b0 : lane == 1 ? b1 : lane == 2 ? b2 : b3;
    bitsT[(size_t)(sub * 4 + lane) * N_TOK + row] = bl;
  }
}

// ---------------- fp32 -> f16 bulk convert (once, up front) ------------------
__global__ __launch_bounds__(256) void convert_kernel(
    const float* __restrict__ s0, const float* __restrict__ s1,
    const float* __restrict__ s2, const float* __restrict__ s3,
    const float* __restrict__ s4, const float* __restrict__ s5,
    const float* __restrict__ s6, unsigned short* __restrict__ d0,
    unsigned short* __restrict__ d1, unsigned short* __restrict__ d2,
    unsigned short* __restrict__ d3, unsigned short* __restrict__ d4,
    unsigned short* __restrict__ d5, unsigned short* __restrict__ d6) {
  int z = blockIdx.y;
  int nblk = (z < 3) ? 1024 : 128;
  if (blockIdx.x >= nblk) return;
  const float* src = z == 0 ? s0 : z == 1 ? s1 : z == 2 ? s2 : z == 3 ? s3
                     : z == 4 ? s4 : z == 5 ? s5 : s6;
  unsigned short* dst = z == 0 ? d0 : z == 1 ? d1 : z == 2 ? d2 : z == 3 ? d3
                        : z == 4 ? d4 : z == 5 ? d5 : d6;
  int idx = (blockIdx.x * 256 + threadIdx.x) * 8;
  float4 f0 = *(const float4*)(src + idx);
  float4 f1 = *(const float4*)(src + idx + 4);
  uint4 o;
  o.x = pack_f16(f0.x, f0.y);
  o.y = pack_f16(f0.z, f0.w);
  o.z = pack_f16(f1.x, f1.y);
  o.w = pack_f16(f1.z, f1.w);
  *(uint4*)(dst + idx) = o;
}

// ---------------- GEMM: out[n][o] = (sum_k A[n][k]*W[o][k] + bias[o])*scale --
// A,W f16 K-major. 128(m)x64(n) tile, BK=64, 4 waves 2x2 (wave = 64m x 32n).
// TRANS=1: write f16 transposed per-head: out[h=col>>6][col&63][token].
template <int O32, int TRANS>
__device__ __forceinline__ void gemm_body64(
    const unsigned short* __restrict__ A, const unsigned short* __restrict__ W,
    const float* __restrict__ bias, void* __restrict__ out, float oscale) {
  __shared__ unsigned short As[128 * 72];
  __shared__ unsigned short Bs[64 * 72];
  const int t = threadIdx.x;
  const int lane = t & 63, w = t >> 6;
  const int wm = w & 1, wn = w >> 1;
  const int q4 = lane >> 4, i15 = lane & 15;
  const int m0 = blockIdx.y * 128, n0 = blockIdx.x * 64;
  f32x4 acc[4][2] = {};
  const int sr = t >> 2;
  const int sc = (t & 3) * 16;
  for (int k0 = 0; k0 < 512; k0 += 64) {
    __syncthreads();
#pragma unroll
    for (int p = 0; p < 2; ++p) {
      int row = sr + p * 64;
      const unsigned short* pa = A + (size_t)(m0 + row) * 512 + k0 + sc;
      uint4 a0 = *(const uint4*)pa, a1 = *(const uint4*)(pa + 8);
      *(uint4*)(As + row * 72 + sc) = a0;
      *(uint4*)(As + row * 72 + sc + 8) = a1;
    }
    {
      const unsigned short* pb = W + (size_t)(n0 + sr) * 512 + k0 + sc;
      uint4 b0 = *(const uint4*)pb, b1 = *(const uint4*)(pb + 8);
      *(uint4*)(Bs + sr * 72 + sc) = b0;
      *(uint4*)(Bs + sr * 72 + sc + 8) = b1;
    }
    __syncthreads();
#pragma unroll
    for (int ks = 0; ks < 2; ++ks) {
      f16x8 af[4], bfr[2];
#pragma unroll
      for (int mt = 0; mt < 4; ++mt)
        af[mt] = *(const f16x8*)(As + (wm * 64 + mt * 16 + i15) * 72 + q4 * 8 + ks * 32);
#pragma unroll
      for (int nt = 0; nt < 2; ++nt)
        bfr[nt] = *(const f16x8*)(Bs + (wn * 32 + nt * 16 + i15) * 72 + q4 * 8 + ks * 32);
#pragma unroll
      for (int mt = 0; mt < 4; ++mt)
#pragma unroll
        for (int nt = 0; nt < 2; ++nt)
          acc[mt][nt] = mfma16(af[mt], bfr[nt], acc[mt][nt]);
    }
  }
  // epilogue: C layout col = lane&15 (+16nt+32wn), row = quad*4+reg (+16mt+64wm)
#pragma unroll
  for (int nt = 0; nt < 2; ++nt) {
    int col = n0 + wn * 32 + nt * 16 + i15;
    float bv = bias[col];
    if (TRANS) {
      unsigned short* ob_ = (unsigned short*)out +
                            (size_t)(col >> 6) * (64 * N_TOK) +
                            (size_t)(col & 63) * N_TOK;
#pragma unroll
      for (int mt = 0; mt < 4; ++mt) {
        int rowb = m0 + wm * 64 + mt * 16 + q4 * 4;
        uint2 pr;
        pr.x = pack_f16(acc[mt][nt][0] + bv, acc[mt][nt][1] + bv);
        pr.y = pack_f16(acc[mt][nt][2] + bv, acc[mt][nt][3] + bv);
        *(uint2*)(ob_ + rowb) = pr;
      }
    } else {
#pragma unroll
      for (int mt = 0; mt < 4; ++mt) {
        int rowb = m0 + wm * 64 + mt * 16 + q4 * 4;
#pragma unroll
        for (int rr = 0; rr < 4; ++rr) {
          int idx = (rowb + rr) * 512 + col;
          float val = (acc[mt][nt][rr] + bv) * oscale;
          if (O32) ((float*)out)[idx] = val;
          else ((unsigned short*)out)[idx] = f2h(val);
        }
      }
    }
  }
}

__global__ __launch_bounds__(256) void qkv_gemm_kernel(
    const unsigned short* __restrict__ qc, const unsigned short* __restrict__ kc,
    const unsigned short* __restrict__ vc, const unsigned short* __restrict__ wqc,
    const unsigned short* __restrict__ wkc, const unsigned short* __restrict__ wvc,
    const float* __restrict__ bq, const float* __restrict__ bk,
    const float* __restrict__ bv, unsigned short* __restrict__ outbase) {
  int z = blockIdx.z;
  if (z == 0) {
    gemm_body64<0, 0>(qc, wqc, bq, outbase, QSCALE);
  } else if (z == 1) {
    gemm_body64<0, 0>(kc, wkc, bk, outbase + (size_t)N_TOK * 512, 1.0f);
  } else {
    gemm_body64<0, 1>(vc, wvc, bv, outbase + 2ull * N_TOK * 512, 1.0f);
  }
}

__global__ __launch_bounds__(256) void out_gemm_kernel(
    const unsigned short* __restrict__ A, const unsigned short* __restrict__ W,
    const float* __restrict__ B, float* __restrict__ out) {
  gemm_body64<1, 0>(A, W, B, out, 1.0f);
}

// ---------------- split-KV flash attention -----------------------------------
// Block: 256 threads = 4 waves; 128 q-rows x head x 1024-j chunk (wave = 32
// q-rows; halved vs prev round so grid = 1024 blocks = 4 blocks/CU, doubling
// occupancy for the VALU-bound softmax). Per 64-j tile: K/V staged
// cooperatively into double-buffered LDS, ONE barrier/tile. All LDS addresses
// precomputed per-lane (loop unrolled x2 so the buffer base is a compile-time
// offset immediate); global K/V/mask are running pointers. S^T = K*Q^T,
// p = exp2 (mask select-to--200), pack via v_cvt_pkrtz (1 op per pair),
// PV B-frag = lane's own packed-exp regs, O^T += V^T*P^T.
#define ATTN_BODY(BUF, MWIN, MWOUT)                                           \
  do {                                                                        \
    char* KsB = (char*)(Ks[BUF]);                                             \
    char* VtB = (char*)(Vt[BUF]);                                             \
    *(uint4*)(KsB + ksto0) = kst0;                                            \
    *(uint4*)(KsB + ksto1) = kst1;                                            \
    {                                                                         \
      const unsigned* vs = (const unsigned*)&vst0;                            \
      *(uint2*)(VtB + vsto00) = make_uint2(vs[0], vs[1]);                     \
      *(uint2*)(VtB + vsto01) = make_uint2(vs[2], vs[3]);                     \
    }                                                                         \
    {                                                                         \
      const unsigned* vs = (const unsigned*)&vst1;                            \
      *(uint2*)(VtB + vsto10) = make_uint2(vs[0], vs[1]);                     \
      *(uint2*)(VtB + vsto11) = make_uint2(vs[2], vs[3]);                     \
    }                                                                         \
    __syncthreads();                                                          \
    kst0 = *(const uint4*)(kgp);                                              \
    kst1 = *(const uint4*)(kgp + 8192);                                       \
    vst0 = *(const uint4*)(vgp);                                              \
    vst1 = *(const uint4*)(vgp + 65536);                                      \
    MWOUT[0] = *(const unsigned long long*)(mgp);                             \
    MWOUT[1] = *(const unsigned long long*)(mgp + 128);                       \
    kgp += 65536;                                                             \
    vgp += 128;                                                               \
    mgp += 32768;                                                             \
    unsigned long long mq0 = MWIN[0] >> (q4 * 4);                             \
    unsigned long long mq1 = MWIN[1] >> (q4 * 4);                             \
    unsigned pk[2][8];                                                        \
    _Pragma("unroll") for (int mtj = 0; mtj < 4; ++mtj) {                     \
      f16x8 Kf0 = *(const f16x8*)(KsB + kfo[mtj][0]);                         \
      f16x8 Kf1 = *(const f16x8*)(KsB + kfo[mtj][1]);                         \
      _Pragma("unroll") for (int nt = 0; nt < 2; ++nt) {                      \
        f32x4 s = {0.f, 0.f, 0.f, 0.f};                                       \
        s = mfma16(Kf0, qf[nt][0], s);                                        \
        s = mfma16(Kf1, qf[nt][1], s);                                        \
        unsigned nib =                                                        \
            (unsigned)((nt ? mq1 : mq0) >> (mtj * 16)) & 15u;                 \
        float p0 = fast_exp2((nib & 1u) ? -200.f : s[0]);                     \
        float p1 = fast_exp2((nib & 2u) ? -200.f : s[1]);                     \
        float p2 = fast_exp2((nib & 4u) ? -200.f : s[2]);                     \
        float p3 = fast_exp2((nib & 8u) ? -200.f : s[3]);                     \
        den[nt] += (p0 + p1) + (p2 + p3);                                     \
        pk[nt][mtj * 2] = pack_f16(p0, p1);                                   \
        pk[nt][mtj * 2 + 1] = pack_f16(p2, p3);                               \
      }                                                                       \
    }                                                                         \
    _Pragma("unroll") for (int ks = 0; ks < 2; ++ks) {                        \
      f16x8 Vf[4];                                                            \
      _Pragma("unroll") for (int mtd = 0; mtd < 4; ++mtd) Vf[mtd] =           \
          *(const f16x8*)(VtB + vfo[ks][mtd]);                                \
      _Pragma("unroll") for (int nt = 0; nt < 2; ++nt) {                      \
        union {                                                               \
          unsigned u[4];                                                      \
          f16x8 v;                                                            \
        } pf;                                                                 \
        pf.u[0] = pk[nt][ks * 4 + 0];                                         \
        pf.u[1] = pk[nt][ks * 4 + 1];                                         \
        pf.u[2] = pk[nt][ks * 4 + 2];                                         \
        pf.u[3] = pk[nt][ks * 4 + 3];                                         \
        _Pragma("unroll") for (int mtd = 0; mtd < 4; ++mtd) oacc[mtd][nt] =   \
            mfma16(Vf[mtd], pf.v, oacc[mtd][nt]);                             \
      }                                                                       \
    }                                                                         \
  } while (0)

__global__ __launch_bounds__(256, 2) void attn_kernel(
    const unsigned short* __restrict__ qp, const unsigned short* __restrict__ kp,
    const unsigned short* __restrict__ vpT,
    const unsigned long long* __restrict__ mbT,
    float* __restrict__ Op, float* __restrict__ dp) {
  __shared__ unsigned short Ks[2][64 * 64];
  __shared__ unsigned short Vt[2][64 * 64];
  const int t = threadIdx.x;
  const int l = t & 63, w = t >> 6;
  const int q4 = l >> 4, i15 = l & 15;
  const int iblk = blockIdx.x * 128;
  const int head = blockIdx.y;
  const int chunk = blockIdx.z;
  const int ch = head * 64;
  const int i0 = iblk + w * 32;
  const int ji = l >> 3;
  const int sg = l & 7;
  const int r0 = w * 2;
  const int j0base = chunk * 1024;
  // Q B-fragments in registers for the whole kernel
  f16x8 qf[2][2];
#pragma unroll
  for (int nt = 0; nt < 2; ++nt) {
    const unsigned short* qr = qp + (size_t)(i0 + nt * 16 + i15) * 512 + ch;
#pragma unroll
    for (int ks = 0; ks < 2; ++ks)
      qf[nt][ks] = *(const f16x8*)(qr + ks * 32 + q4 * 8);
  }
  f32x4 oacc[4][2] = {};
  float den[2] = {0.f, 0.f};
  // ---- precomputed lane-constant LDS byte offsets
  int kfo[4][2], vfo[2][4];
#pragma unroll
  for (int mtj = 0; mtj < 4; ++mtj) {
    int js = mtj * 16 + i15;
    int h = (js & 7) ^ (js >> 3);
#pragma unroll
    for (int ksd = 0; ksd < 2; ++ksd)
      kfo[mtj][ksd] = (js * 64 + (((ksd * 4 + q4) ^ h) * 8)) * 2;
  }
#pragma unroll
  for (int ks = 0; ks < 2; ++ks)
#pragma unroll
    for (int mtd = 0; mtd < 4; ++mtd) {
      int d = mtd * 16 + i15;
      int h = (d & 7) ^ (d >> 3);
      vfo[ks][mtd] = (d * 64 + (((ks * 4 + q4) ^ h) * 8)) * 2;
    }
  int ksto0, ksto1, vsto00, vsto01, vsto10, vsto11;
  {
    int r = r0, row = r * 8 + ji;
    ksto0 = (row * 64 + ((sg ^ ji ^ r) * 8)) * 2;
    int hh = (sg >> 1) & 1;
    int kg0 = (sg >> 2) * 4 + (sg & 1) * 2;
    vsto00 = (row * 64 + ((kg0 ^ ji ^ r) * 8) + hh * 4) * 2;
    vsto01 = (row * 64 + (((kg0 + 1) ^ ji ^ r) * 8) + hh * 4) * 2;
    r = r0 + 1; row = r * 8 + ji;
    ksto1 = (row * 64 + ((sg ^ ji ^ r) * 8)) * 2;
    vsto10 = (row * 64 + ((kg0 ^ ji ^ r) * 8) + hh * 4) * 2;
    vsto11 = (row * 64 + (((kg0 + 1) ^ ji ^ r) * 8) + hh * 4) * 2;
  }
  // ---- running global pointers (advance by constant stride per tile)
  const char* kgp =
      (const char*)kp + ((size_t)(j0base + r0 * 8 + ji) * 512 + ch + sg * 8) * 2;
  const char* vgp = (const char*)(vpT + (size_t)head * 64 * N_TOK) +
                    ((size_t)(r0 * 8 + ji) * N_TOK + j0base + sg * 8) * 2;
  const char* mgp =
      (const char*)mbT + ((size_t)(chunk * 16) * N_TOK + i0 + i15) * 8;
  uint4 kst0, kst1, vst0, vst1;
  unsigned long long mwc[2], mwn[2];
  // prefetch tile 0 (+ its mask words)
  kst0 = *(const uint4*)(kgp);
  kst1 = *(const uint4*)(kgp + 8192);
  vst0 = *(const uint4*)(vgp);
  vst1 = *(const uint4*)(vgp + 65536);
  mwc[0] = *(const unsigned long long*)(mgp);
  mwc[1] = *(const unsigned long long*)(mgp + 128);
  kgp += 65536;
  vgp += 128;
  mgp += 32768;
  // 16 tiles, unrolled x2 (double-buffer base = compile-time offset).
  // Final bodies prefetch past the chunk end -- lands in adjacent mapped
  // workspace regions, loaded into regs but never consumed.
  for (int jp = 0; jp < 8; ++jp) {
    ATTN_BODY(0, mwc, mwn);
    ATTN_BODY(1, mwn, mwc);
  }
  // ---- write fp32 partials: Op[chunk][head][i][64], dp[chunk][head][i]
  float* Opc = Op + ((size_t)(chunk * 8 + head) * N_TOK) * 64;
#pragma unroll
  for (int nt = 0; nt < 2; ++nt) {
    float dn = den[nt];
    dn += __shfl_xor(dn, 16);
    dn += __shfl_xor(dn, 32);
    int row = i0 + nt * 16 + i15;
#pragma unroll
    for (int mtd = 0; mtd < 4; ++mtd)
      *(f32x4*)(Opc + (size_t)row * 64 + mtd * 16 + q4 * 4) = oacc[mtd][nt];
    if (q4 == 0) dp[(size_t)(chunk * 8 + head) * N_TOK + row] = dn;
  }
}

// ---------------- combine split-KV partials -> f16 attention output ----------
__global__ __launch_bounds__(256) void reduce_kernel(
    const float* __restrict__ Op, const float* __restrict__ dp,
    unsigned short* __restrict__ ob) {
  int x = blockIdx.x * 256 + threadIdx.x;  // 0..524287
  int i = x >> 7;
  int c = (x & 127) * 4;
  int h = c >> 6;
  int d = c & 63;
  const size_t CH = (size_t)8 * N_TOK * 64;  // floats per chunk
  size_t base = ((size_t)h * N_TOK + i) * 64 + d;
  float4 a0 = *(const float4*)(Op + base);
  float4 a1 = *(const float4*)(Op + CH + base);
  float4 a2 = *(const float4*)(Op + 2 * CH + base);
  float4 a3 = *(const float4*)(Op + 3 * CH + base);
  float den = dp[(size_t)h * N_TOK + i] + dp[(size_t)(8 + h) * N_TOK + i] +
              dp[(size_t)(16 + h) * N_TOK + i] + dp[(size_t)(24 + h) * N_TOK + i];
  float inv = 1.0f / den;
  float sx = (a0.x + a1.x + a2.x + a3.x) * inv;
  float sy = (a0.y + a1.y + a2.y + a3.y) * inv;
  float sz = (a0.z + a1.z + a2.z + a3.z) * inv;
  float sw = (a0.w + a1.w + a2.w + a3.w) * inv;
  uint2 o;
  o.x = pack_f16(sx, sy);
  o.y = pack_f16(sz, sw);
  *(uint2*)(ob + (size_t)i * 512 + c) = o;
}

// ---------------- launch -----------------------------------------------------
extern "C" void kernel_launch(void* const* d_in, const int* in_sizes, int n_in,
                              void* d_out, int out_size, void* d_ws, size_t ws_size,
                              hipStream_t stream) {
  const float* q = (const float*)d_in[0];
  const float* k = (const float*)d_in[1];
  const float* v = (const float*)d_in[2];
  const int* mask = (const int*)d_in[3];
  const float* wq = (const float*)d_in[4];
  const float* bq = (const float*)d_in[5];
  const float* wk = (const float*)d_in[6];
  const float* bk = (const float*)d_in[7];
  const float* wv = (const float*)d_in[8];
  const float* bv = (const float*)d_in[9];
  const float* wo = (const float*)d_in[10];
  const float* bo = (const float*)d_in[11];

  char* ws = (char*)d_ws;
  const size_t MB = 1ull << 20;
  unsigned short* woc = (unsigned short*)(ws + 4096);     // 512 KiB
  unsigned long long* mbT = (unsigned long long*)(ws + 1 * MB);  // 2 MiB
  unsigned short* qkvp = (unsigned short*)(ws + 3 * MB);  // 12 MiB: qp,kp,vpT
  unsigned short* ob = (unsigned short*)(ws + 15 * MB);   // 4 MiB
  unsigned short* qc = (unsigned short*)(ws + 19 * MB);   // 4 MiB
  unsigned short* kc = (unsigned short*)(ws + 23 * MB);   // 4 MiB
  unsigned short* vc = (unsigned short*)(ws + 27 * MB);   // 4 MiB
  unsigned short* wqc = (unsigned short*)(ws + 31 * MB);  // 512 KiB
  unsigned short* wkc = (unsigned short*)(ws + 31 * MB + 512 * 1024);
  unsigned short* wvc = (unsigned short*)(ws + 32 * MB);
  float* Op = (float*)(ws + 19 * MB);                     // 32 MiB (aliases qc..)
  float* dp = (float*)(ws + 51 * MB);                     // 512 KiB

  pack_mask_kernel<<<16384, 256, 0, stream>>>(mask, mbT);
  convert_kernel<<<dim3(1024, 7), 256, 0, stream>>>(
      q, k, v, wq, wk, wv, wo, qc, kc, vc, wqc, wkc, wvc, woc);
  qkv_gemm_kernel<<<dim3(8, 32, 3), 256, 0, stream>>>(qc, kc, vc, wqc, wkc,
                                                      wvc, bq, bk, bv, qkvp);
  attn_kernel<<<dim3(32, 8, 4), 256, 0, stream>>>(
      qkvp, qkvp + (size_t)N_TOK * 512, qkvp + 2ull * N_TOK * 512, mbT, Op, dp);
  reduce_kernel<<<2048, 256, 0, stream>>>(Op, dp, ob);
  out_gemm_kernel<<<dim3(8, 32), 256, 0, stream>>>(ob, woc, bo, (float*)d_out);
}

// Round 4
// 223.207 us; speedup vs baseline: 1.0922x; 1.0781x over previous
//
#include <hip/hip_runtime.h>

// MultiheadAttention N=4096, d_model=512, 8 heads, d_head=64.
// fp32 inputs/output, f16 MFMA pipeline.
// pack_mask -> transposed 2MB bitmap mbT[word][row] ; convert fp32->f16 ;
// qkv GEMM 128x64 tile with global_load_lds(16B) staging (pre-swizzled
// global source + XOR-swizzled ds_read, linear LDS dest -- m97 recipe) ;
// split-KV flash attention (4-wave blocks, 128 q-rows/block = 4 blocks/CU,
// double-buffered staging, hoisted LDS addressing, running global pointers,
// zero-shuffle PV, direct [nt][ks] pack unions, s_setprio around MFMA) ;
// reduce partials ; output GEMM.

typedef __attribute__((ext_vector_type(8))) _Float16 f16x8;
typedef __attribute__((ext_vector_type(2))) __fp16 fp16x2_raw;  // cvt_pkrtz ret
typedef __attribute__((ext_vector_type(4))) float f32x4;

union pku_t { unsigned u[4]; f16x8 v; };

#define N_TOK 4096
#define QSCALE 0.18033688f  // 0.125 * log2(e)

__device__ __forceinline__ unsigned short f2h(float f) {
  union { _Float16 h; unsigned short u; } c;
  c.h = (_Float16)f;
  return c.u;
}
// packed f32x2 -> f16x2 in ONE instruction (v_cvt_pkrtz_f16_f32).
__device__ __forceinline__ unsigned pack_f16(float a, float b) {
  union { fp16x2_raw h; unsigned u; } c;
  c.h = __builtin_amdgcn_cvt_pkrtz(a, b);
  return c.u;
}
__device__ __forceinline__ f32x4 mfma16(f16x8 a, f16x8 b, f32x4 c) {
  return __builtin_amdgcn_mfma_f32_16x16x32_f16(a, b, c, 0, 0, 0);
}
__device__ __forceinline__ float fast_exp2(float x) {
#if __has_builtin(__builtin_amdgcn_exp2f)
  return __builtin_amdgcn_exp2f(x);
#else
  return exp2f(x);
#endif
}
// async global->LDS, 16B per lane; LDS dest is wave-uniform base + lane*16.
__device__ __forceinline__ void gload_lds16(const void* g, void* l) {
  __builtin_amdgcn_global_load_lds(
      (const __attribute__((address_space(1))) void*)g,
      (__attribute__((address_space(3))) void*)l, 16, 0, 0);
}

// ---------------- mask bit-pack -> TRANSPOSED u64 bitsT[64 words][4096 rows] -
// mask proven int32 {0,1} by rounds 2-7 (u8 misread would fail absmax).
__global__ __launch_bounds__(256) void pack_mask_kernel(
    const int* __restrict__ m, unsigned long long* __restrict__ bitsT) {
  int gt = blockIdx.x * 256 + threadIdx.x;
  int wave = gt >> 6;       // 0..65535
  int lane = threadIdx.x & 63;
  int row = wave >> 4;      // mask row
  int sub = wave & 15;      // 256-elem j-slice within the row
  int base = wave * 256;
  unsigned long long b0 = __ballot(m[base + 0 * 64 + lane] != 0);
  unsigned long long b1 = __ballot(m[base + 1 * 64 + lane] != 0);
  unsigned long long b2 = __ballot(m[base + 2 * 64 + lane] != 0);
  unsigned long long b3 = __ballot(m[base + 3 * 64 + lane] != 0);
  if (lane < 4) {
    unsigned long long bl = lane == 0 ? b0 : lane == 1 ? b1 : lane == 2 ? b2 : b3;
    bitsT[(size_t)(sub * 4 + lane) * N_TOK + row] = bl;
  }
}

// ---------------- fp32 -> f16 bulk convert (once, up front) ------------------
__global__ __launch_bounds__(256) void convert_kernel(
    const float* __restrict__ s0, const float* __restrict__ s1,
    const float* __restrict__ s2, const float* __restrict__ s3,
    const float* __restrict__ s4, const float* __restrict__ s5,
    const float* __restrict__ s6, unsigned short* __restrict__ d0,
    unsigned short* __restrict__ d1, unsigned short* __restrict__ d2,
    unsigned short* __restrict__ d3, unsigned short* __restrict__ d4,
    unsigned short* __restrict__ d5, unsigned short* __restrict__ d6) {
  int z = blockIdx.y;
  int nblk = (z < 3) ? 1024 : 128;
  if (blockIdx.x >= nblk) return;
  const float* src = z == 0 ? s0 : z == 1 ? s1 : z == 2 ? s2 : z == 3 ? s3
                     : z == 4 ? s4 : z == 5 ? s5 : s6;
  unsigned short* dst = z == 0 ? d0 : z == 1 ? d1 : z == 2 ? d2 : z == 3 ? d3
                        : z == 4 ? d4 : z == 5 ? d5 : d6;
  int idx = (blockIdx.x * 256 + threadIdx.x) * 8;
  float4 f0 = *(const float4*)(src + idx);
  float4 f1 = *(const float4*)(src + idx + 4);
  uint4 o;
  o.x = pack_f16(f0.x, f0.y);
  o.y = pack_f16(f0.z, f0.w);
  o.z = pack_f16(f1.x, f1.y);
  o.w = pack_f16(f1.z, f1.w);
  *(uint4*)(dst + idx) = o;
}

// ---------------- GEMM: out[n][o] = (sum_k A[n][k]*W[o][k] + bias[o])*scale --
// A,W f16 K-major. 128(m)x64(n) tile, BK=64, 4 waves 2x2 (wave = 64m x 32n).
// Staging: global_load_lds 16B/lane, linear LDS [rows][64] shorts; the 16B
// unit column is XOR-swizzled by (row&7) on the GLOBAL source so ds_reads
// (same XOR) are 2-way-conflict-free (both-sides swizzle, m97/m173 pattern).
// TRANS=1: write f16 transposed per-head: out[h=col>>6][col&63][token].
template <int O32, int TRANS>
__device__ __forceinline__ void gemm_body64(
    const unsigned short* __restrict__ A, const unsigned short* __restrict__ W,
    const float* __restrict__ bias, void* __restrict__ out, float oscale) {
  __shared__ __align__(16) unsigned short As[128 * 64];
  __shared__ __align__(16) unsigned short Bs[64 * 64];
  const int t = threadIdx.x;
  const int lane = t & 63, w = t >> 6;
  const int wm = w & 1, wn = w >> 1;
  const int q4 = lane >> 4, i15 = lane & 15;
  const int m0 = blockIdx.y * 128, n0 = blockIdx.x * 64;
  f32x4 acc[4][2] = {};
  // staging geometry: each gload_lds16 covers 8 rows x 64 shorts (1 KiB).
  // lane -> row_local = lane>>3, unit = lane&7; source unit pre-swizzled
  // by row_local so linear LDS holds the swizzled image.
  const int lr = lane >> 3;
  const int su = (lane & 7) ^ lr;
  const unsigned short* agp = A + (size_t)(m0 + w * 32 + lr) * 512 + su * 8;
  const unsigned short* bgp = W + (size_t)(n0 + w * 16 + lr) * 512 + su * 8;
  unsigned short* asb = As + (w * 32) * 64;
  unsigned short* bsb = Bs + (w * 16) * 64;
  const int h8 = i15 & 7;  // read-side swizzle key
  for (int k0 = 0; k0 < 512; k0 += 64) {
    __syncthreads();  // previous tile's reads done (drains lgkm+vm)
#pragma unroll
    for (int i = 0; i < 4; ++i)
      gload_lds16(agp + i * 8 * 512 + k0, asb + i * 8 * 64);
#pragma unroll
    for (int i = 0; i < 2; ++i)
      gload_lds16(bgp + i * 8 * 512 + k0, bsb + i * 8 * 64);
    __syncthreads();  // barrier drain waits vmcnt(0) -> LDS tile ready
#pragma unroll
    for (int ks = 0; ks < 2; ++ks) {
      f16x8 af[4], bfr[2];
#pragma unroll
      for (int mt = 0; mt < 4; ++mt)
        af[mt] = *(const f16x8*)(As + (wm * 64 + mt * 16 + i15) * 64 +
                                 (((ks * 4 + q4) ^ h8) * 8));
#pragma unroll
      for (int nt = 0; nt < 2; ++nt)
        bfr[nt] = *(const f16x8*)(Bs + (wn * 32 + nt * 16 + i15) * 64 +
                                  (((ks * 4 + q4) ^ h8) * 8));
#pragma unroll
      for (int mt = 0; mt < 4; ++mt)
#pragma unroll
        for (int nt = 0; nt < 2; ++nt)
          acc[mt][nt] = mfma16(af[mt], bfr[nt], acc[mt][nt]);
    }
  }
  // epilogue: C layout col = lane&15 (+16nt+32wn), row = quad*4+reg (+16mt+64wm)
#pragma unroll
  for (int nt = 0; nt < 2; ++nt) {
    int col = n0 + wn * 32 + nt * 16 + i15;
    float bv = bias[col];
    if (TRANS) {
      unsigned short* ob_ = (unsigned short*)out +
                            (size_t)(col >> 6) * (64 * N_TOK) +
                            (size_t)(col & 63) * N_TOK;
#pragma unroll
      for (int mt = 0; mt < 4; ++mt) {
        int rowb = m0 + wm * 64 + mt * 16 + q4 * 4;
        uint2 pr;
        pr.x = pack_f16(acc[mt][nt][0] + bv, acc[mt][nt][1] + bv);
        pr.y = pack_f16(acc[mt][nt][2] + bv, acc[mt][nt][3] + bv);
        *(uint2*)(ob_ + rowb) = pr;
      }
    } else {
#pragma unroll
      for (int mt = 0; mt < 4; ++mt) {
        int rowb = m0 + wm * 64 + mt * 16 + q4 * 4;
#pragma unroll
        for (int rr = 0; rr < 4; ++rr) {
          int idx = (rowb + rr) * 512 + col;
          float val = (acc[mt][nt][rr] + bv) * oscale;
          if (O32) ((float*)out)[idx] = val;
          else ((unsigned short*)out)[idx] = f2h(val);
        }
      }
    }
  }
}

__global__ __launch_bounds__(256) void qkv_gemm_kernel(
    const unsigned short* __restrict__ qc, const unsigned short* __restrict__ kc,
    const unsigned short* __restrict__ vc, const unsigned short* __restrict__ wqc,
    const unsigned short* __restrict__ wkc, const unsigned short* __restrict__ wvc,
    const float* __restrict__ bq, const float* __restrict__ bk,
    const float* __restrict__ bv, unsigned short* __restrict__ outbase) {
  int z = blockIdx.z;
  if (z == 0) {
    gemm_body64<0, 0>(qc, wqc, bq, outbase, QSCALE);
  } else if (z == 1) {
    gemm_body64<0, 0>(kc, wkc, bk, outbase + (size_t)N_TOK * 512, 1.0f);
  } else {
    gemm_body64<0, 1>(vc, wvc, bv, outbase + 2ull * N_TOK * 512, 1.0f);
  }
}

__global__ __launch_bounds__(256) void out_gemm_kernel(
    const unsigned short* __restrict__ A, const unsigned short* __restrict__ W,
    const float* __restrict__ B, float* __restrict__ out) {
  gemm_body64<1, 0>(A, W, B, out, 1.0f);
}

// ---------------- split-KV flash attention -----------------------------------
// Block: 256 threads = 4 waves; 128 q-rows x head x 1024-j chunk (4 blocks/CU).
// Per 64-j tile: K/V staged cooperatively into double-buffered LDS, ONE
// barrier/tile. All LDS addresses precomputed per-lane (loop unrolled x2 so
// the buffer base is a compile-time offset immediate); global K/V/mask are
// running pointers. S^T = K*Q^T, p = exp2 (mask select-to--200), pack via
// v_cvt_pkrtz directly into [nt][ks] unions (PV B-frag = those regs, no
// repack), s_setprio(1) around MFMA clusters (T5), O^T += V^T*P^T.
#define ATTN_BODY(BUF, MWIN, MWOUT)                                           \
  do {                                                                        \
    char* KsB = (char*)(Ks[BUF]);                                             \
    char* VtB = (char*)(Vt[BUF]);                                             \
    *(uint4*)(KsB + ksto0) = kst0;                                            \
    *(uint4*)(KsB + ksto1) = kst1;                                            \
    {                                                                         \
      const unsigned* vs = (const unsigned*)&vst0;                            \
      *(uint2*)(VtB + vsto00) = make_uint2(vs[0], vs[1]);                     \
      *(uint2*)(VtB + vsto01) = make_uint2(vs[2], vs[3]);                     \
    }                                                                         \
    {                                                                         \
      const unsigned* vs = (const unsigned*)&vst1;                            \
      *(uint2*)(VtB + vsto10) = make_uint2(vs[0], vs[1]);                     \
      *(uint2*)(VtB + vsto11) = make_uint2(vs[2], vs[3]);                     \
    }                                                                         \
    __syncthreads();                                                          \
    kst0 = *(const uint4*)(kgp);                                              \
    kst1 = *(const uint4*)(kgp + 8192);                                       \
    vst0 = *(const uint4*)(vgp);                                              \
    vst1 = *(const uint4*)(vgp + 65536);                                      \
    MWOUT[0] = *(const unsigned long long*)(mgp);                             \
    MWOUT[1] = *(const unsigned long long*)(mgp + 128);                       \
    kgp += 65536;                                                             \
    vgp += 128;                                                               \
    mgp += 32768;                                                             \
    unsigned long long mq0 = MWIN[0] >> (q4 * 4);                             \
    unsigned long long mq1 = MWIN[1] >> (q4 * 4);                             \
    pku_t pk[2][2];                                                           \
    _Pragma("unroll") for (int mtj = 0; mtj < 4; ++mtj) {                     \
      f16x8 Kf0 = *(const f16x8*)(KsB + kfo[mtj][0]);                         \
      f16x8 Kf1 = *(const f16x8*)(KsB + kfo[mtj][1]);                         \
      _Pragma("unroll") for (int nt = 0; nt < 2; ++nt) {                      \
        f32x4 s = {0.f, 0.f, 0.f, 0.f};                                       \
        __builtin_amdgcn_s_setprio(1);                                        \
        s = mfma16(Kf0, qf[nt][0], s);                                        \
        s = mfma16(Kf1, qf[nt][1], s);                                        \
        __builtin_amdgcn_s_setprio(0);                                        \
        unsigned nib =                                                        \
            (unsigned)((nt ? mq1 : mq0) >> (mtj * 16)) & 15u;                 \
        float p0 = fast_exp2((nib & 1u) ? -200.f : s[0]);                     \
        float p1 = fast_exp2((nib & 2u) ? -200.f : s[1]);                     \
        float p2 = fast_exp2((nib & 4u) ? -200.f : s[2]);                     \
        float p3 = fast_exp2((nib & 8u) ? -200.f : s[3]);                     \
        den[nt] += (p0 + p1) + (p2 + p3);                                     \
        pk[nt][mtj >> 1].u[(mtj & 1) * 2] = pack_f16(p0, p1);                 \
        pk[nt][mtj >> 1].u[(mtj & 1) * 2 + 1] = pack_f16(p2, p3);             \
      }                                                                       \
    }                                                                         \
    __builtin_amdgcn_s_setprio(1);                                            \
    _Pragma("unroll") for (int ks = 0; ks < 2; ++ks) {                        \
      f16x8 Vf[4];                                                            \
      _Pragma("unroll") for (int mtd = 0; mtd < 4; ++mtd) Vf[mtd] =           \
          *(const f16x8*)(VtB + vfo[ks][mtd]);                                \
      _Pragma("unroll") for (int nt = 0; nt < 2; ++nt) {                      \
        _Pragma("unroll") for (int mtd = 0; mtd < 4; ++mtd) oacc[mtd][nt] =   \
            mfma16(Vf[mtd], pk[nt][ks].v, oacc[mtd][nt]);                     \
      }                                                                       \
    }                                                                         \
    __builtin_amdgcn_s_setprio(0);                                            \
  } while (0)

__global__ __launch_bounds__(256, 2) void attn_kernel(
    const unsigned short* __restrict__ qp, const unsigned short* __restrict__ kp,
    const unsigned short* __restrict__ vpT,
    const unsigned long long* __restrict__ mbT,
    float* __restrict__ Op, float* __restrict__ dp) {
  __shared__ unsigned short Ks[2][64 * 64];
  __shared__ unsigned short Vt[2][64 * 64];
  const int t = threadIdx.x;
  const int l = t & 63, w = t >> 6;
  const int q4 = l >> 4, i15 = l & 15;
  const int iblk = blockIdx.x * 128;
  const int head = blockIdx.y;
  const int chunk = blockIdx.z;
  const int ch = head * 64;
  const int i0 = iblk + w * 32;
  const int ji = l >> 3;
  const int sg = l & 7;
  const int r0 = w * 2;
  const int j0base = chunk * 1024;
  // Q B-fragments in registers for the whole kernel
  f16x8 qf[2][2];
#pragma unroll
  for (int nt = 0; nt < 2; ++nt) {
    const unsigned short* qr = qp + (size_t)(i0 + nt * 16 + i15) * 512 + ch;
#pragma unroll
    for (int ks = 0; ks < 2; ++ks)
      qf[nt][ks] = *(const f16x8*)(qr + ks * 32 + q4 * 8);
  }
  f32x4 oacc[4][2] = {};
  float den[2] = {0.f, 0.f};
  // ---- precomputed lane-constant LDS byte offsets
  int kfo[4][2], vfo[2][4];
#pragma unroll
  for (int mtj = 0; mtj < 4; ++mtj) {
    int js = mtj * 16 + i15;
    int h = (js & 7) ^ (js >> 3);
#pragma unroll
    for (int ksd = 0; ksd < 2; ++ksd)
      kfo[mtj][ksd] = (js * 64 + (((ksd * 4 + q4) ^ h) * 8)) * 2;
  }
#pragma unroll
  for (int ks = 0; ks < 2; ++ks)
#pragma unroll
    for (int mtd = 0; mtd < 4; ++mtd) {
      int d = mtd * 16 + i15;
      int h = (d & 7) ^ (d >> 3);
      vfo[ks][mtd] = (d * 64 + (((ks * 4 + q4) ^ h) * 8)) * 2;
    }
  int ksto0, ksto1, vsto00, vsto01, vsto10, vsto11;
  {
    int r = r0, row = r * 8 + ji;
    ksto0 = (row * 64 + ((sg ^ ji ^ r) * 8)) * 2;
    int hh = (sg >> 1) & 1;
    int kg0 = (sg >> 2) * 4 + (sg & 1) * 2;
    vsto00 = (row * 64 + ((kg0 ^ ji ^ r) * 8) + hh * 4) * 2;
    vsto01 = (row * 64 + (((kg0 + 1) ^ ji ^ r) * 8) + hh * 4) * 2;
    r = r0 + 1; row = r * 8 + ji;
    ksto1 = (row * 64 + ((sg ^ ji ^ r) * 8)) * 2;
    vsto10 = (row * 64 + ((kg0 ^ ji ^ r) * 8) + hh * 4) * 2;
    vsto11 = (row * 64 + (((kg0 + 1) ^ ji ^ r) * 8) + hh * 4) * 2;
  }
  // ---- running global pointers (advance by constant stride per tile)
  const char* kgp =
      (const char*)kp + ((size_t)(j0base + r0 * 8 + ji) * 512 + ch + sg * 8) * 2;
  const char* vgp = (const char*)(vpT + (size_t)head * 64 * N_TOK) +
                    ((size_t)(r0 * 8 + ji) * N_TOK + j0base + sg * 8) * 2;
  const char* mgp =
      (const char*)mbT + ((size_t)(chunk * 16) * N_TOK + i0 + i15) * 8;
  uint4 kst0, kst1, vst0, vst1;
  unsigned long long mwc[2], mwn[2];
  // prefetch tile 0 (+ its mask words)
  kst0 = *(const uint4*)(kgp);
  kst1 = *(const uint4*)(kgp + 8192);
  vst0 = *(const uint4*)(vgp);
  vst1 = *(const uint4*)(vgp + 65536);
  mwc[0] = *(const unsigned long long*)(mgp);
  mwc[1] = *(const unsigned long long*)(mgp + 128);
  kgp += 65536;
  vgp += 128;
  mgp += 32768;
  // 16 tiles, unrolled x2 (double-buffer base = compile-time offset).
  // Final bodies prefetch past the chunk end -- lands in adjacent mapped
  // workspace regions, loaded into regs but never consumed.
  for (int jp = 0; jp < 8; ++jp) {
    ATTN_BODY(0, mwc, mwn);
    ATTN_BODY(1, mwn, mwc);
  }
  // ---- write fp32 partials: Op[chunk][head][i][64], dp[chunk][head][i]
  float* Opc = Op + ((size_t)(chunk * 8 + head) * N_TOK) * 64;
#pragma unroll
  for (int nt = 0; nt < 2; ++nt) {
    float dn = den[nt];
    dn += __shfl_xor(dn, 16);
    dn += __shfl_xor(dn, 32);
    int row = i0 + nt * 16 + i15;
#pragma unroll
    for (int mtd = 0; mtd < 4; ++mtd)
      *(f32x4*)(Opc + (size_t)row * 64 + mtd * 16 + q4 * 4) = oacc[mtd][nt];
    if (q4 == 0) dp[(size_t)(chunk * 8 + head) * N_TOK + row] = dn;
  }
}

// ---------------- combine split-KV partials -> f16 attention output ----------
__global__ __launch_bounds__(256) void reduce_kernel(
    const float* __restrict__ Op, const float* __restrict__ dp,
    unsigned short* __restrict__ ob) {
  int x = blockIdx.x * 256 + threadIdx.x;  // 0..524287
  int i = x >> 7;
  int c = (x & 127) * 4;
  int h = c >> 6;
  int d = c & 63;
  const size_t CH = (size_t)8 * N_TOK * 64;  // floats per chunk
  size_t base = ((size_t)h * N_TOK + i) * 64 + d;
  float4 a0 = *(const float4*)(Op + base);
  float4 a1 = *(const float4*)(Op + CH + base);
  float4 a2 = *(const float4*)(Op + 2 * CH + base);
  float4 a3 = *(const float4*)(Op + 3 * CH + base);
  float den = dp[(size_t)h * N_TOK + i] + dp[(size_t)(8 + h) * N_TOK + i] +
              dp[(size_t)(16 + h) * N_TOK + i] + dp[(size_t)(24 + h) * N_TOK + i];
  float inv = 1.0f / den;
  float sx = (a0.x + a1.x + a2.x + a3.x) * inv;
  float sy = (a0.y + a1.y + a2.y + a3.y) * inv;
  float sz = (a0.z + a1.z + a2.z + a3.z) * inv;
  float sw = (a0.w + a1.w + a2.w + a3.w) * inv;
  uint2 o;
  o.x = pack_f16(sx, sy);
  o.y = pack_f16(sz, sw);
  *(uint2*)(ob + (size_t)i * 512 + c) = o;
}

// ---------------- launch -----------------------------------------------------
extern "C" void kernel_launch(void* const* d_in, const int* in_sizes, int n_in,
                              void* d_out, int out_size, void* d_ws, size_t ws_size,
                              hipStream_t stream) {
  const float* q = (const float*)d_in[0];
  const float* k = (const float*)d_in[1];
  const float* v = (const float*)d_in[2];
  const int* mask = (const int*)d_in[3];
  const float* wq = (const float*)d_in[4];
  const float* bq = (const float*)d_in[5];
  const float* wk = (const float*)d_in[6];
  const float* bk = (const float*)d_in[7];
  const float* wv = (const float*)d_in[8];
  const float* bv = (const float*)d_in[9];
  const float* wo = (const float*)d_in[10];
  const float* bo = (const float*)d_in[11];

  char* ws = (char*)d_ws;
  const size_t MB = 1ull << 20;
  unsigned short* woc = (unsigned short*)(ws + 4096);     // 512 KiB
  unsigned long long* mbT = (unsigned long long*)(ws + 1 * MB);  // 2 MiB
  unsigned short* qkvp = (unsigned short*)(ws + 3 * MB);  // 12 MiB: qp,kp,vpT
  unsigned short* ob = (unsigned short*)(ws + 15 * MB);   // 4 MiB
  unsigned short* qc = (unsigned short*)(ws + 19 * MB);   // 4 MiB
  unsigned short* kc = (unsigned short*)(ws + 23 * MB);   // 4 MiB
  unsigned short* vc = (unsigned short*)(ws + 27 * MB);   // 4 MiB
  unsigned short* wqc = (unsigned short*)(ws + 31 * MB);  // 512 KiB
  unsigned short* wkc = (unsigned short*)(ws + 31 * MB + 512 * 1024);
  unsigned short* wvc = (unsigned short*)(ws + 32 * MB);
  float* Op = (float*)(ws + 19 * MB);                     // 32 MiB (aliases qc..)
  float* dp = (float*)(ws + 51 * MB);                     // 512 KiB

  pack_mask_kernel<<<16384, 256, 0, stream>>>(mask, mbT);
  convert_kernel<<<dim3(1024, 7), 256, 0, stream>>>(
      q, k, v, wq, wk, wv, wo, qc, kc, vc, wqc, wkc, wvc, woc);
  qkv_gemm_kernel<<<dim3(8, 32, 3), 256, 0, stream>>>(qc, kc, vc, wqc, wkc,
                                                      wvc, bq, bk, bv, qkvp);
  attn_kernel<<<dim3(32, 8, 4), 256, 0, stream>>>(
      qkvp, qkvp + (size_t)N_TOK * 512, qkvp + 2ull * N_TOK * 512, mbT, Op, dp);
  reduce_kernel<<<2048, 256, 0, stream>>>(Op, dp, ob);
  out_gemm_kernel<<<dim3(8, 32), 256, 0, stream>>>(ob, woc, bo, (float*)d_out);
}